// Round 12
// baseline (315.406 us; speedup 1.0000x reference)
//
#include <hip/hip_runtime.h>
#include <cstddef>

#define NN 25600
#define BB 64
#define NPG 400
#define KK 16
#define LL 4

typedef _Float16 half_t;
typedef _Float16 h8 __attribute__((ext_vector_type(8)));
typedef _Float16 h4 __attribute__((ext_vector_type(4)));
typedef _Float16 h2 __attribute__((ext_vector_type(2)));
typedef float f32x4 __attribute__((ext_vector_type(4)));

// ---------------- weight prep ----------------------------------------------
// Wk1H/L  [L][3][8 c16][4 kc][64][8]: slab0 = Wpre A-side, slab1 = Wpre B-side,
//          slab2 = Wpost h-part (k 0..127). 16384 halves per slab per plane.
// WaggH/L [L][8 c16][12 kc][64][8]: Wpost agg-part, k 0..383 = [mean/16+s|mx|dir].
__global__ __launch_bounds__(256) void prep_k(const float* __restrict__ preW,
                                              const float* __restrict__ postW,
                                              half_t* __restrict__ Wk1H,
                                              half_t* __restrict__ Wk1L,
                                              half_t* __restrict__ WaggH,
                                              half_t* __restrict__ WaggL) {
  const int idx = blockIdx.x * 256 + threadIdx.x;
  const int n1 = LL * 3 * 16384;  // 196608
  if (idx < n1) {
    int l = idx / 49152;
    int q = idx % 49152;
    int slab = q / 16384;
    int qq = q & 16383;
    int j = qq & 7, lane = (qq >> 3) & 63, kc = (qq >> 9) & 3, c16 = qq >> 11;  // 0..7
    int col = c16 * 16 + (lane & 15);
    int k = kc * 32 + (lane >> 4) * 8 + j;
    float v;
    if (slab == 0)      v = preW[(size_t)l * 32768 + (size_t)col * 256 + k];
    else if (slab == 1) v = preW[(size_t)l * 32768 + (size_t)col * 256 + 128 + k];
    else                v = postW[(size_t)l * 81920 + (size_t)col * 640 + k];
    half_t hi = (half_t)v;
    Wk1H[idx] = hi;
    Wk1L[idx] = (half_t)(v - (float)hi);
  } else if (idx < 2 * n1) {
    int r = idx - n1;
    int l = r / 49152;
    int q = r % 49152;
    int c16 = q / 6144;
    int rr = q % 6144;
    int kc = rr >> 9, lane = (rr >> 3) & 63, j = rr & 7;
    int col = c16 * 16 + (lane & 15);
    int k = kc * 32 + (lane >> 4) * 8 + j;
    int kk = k & 127, jb = k >> 7;
    const float* base = postW + (size_t)l * 81920 + (size_t)col * 640;
    float v;
    if (jb == 0)      v = base[128 + kk] * (1.f / 16.f) + base[256 + kk];
    else if (jb == 1) v = base[384 + kk];
    else              v = base[512 + kk];
    half_t hi = (half_t)v;
    WaggH[r] = hi;
    WaggL[r] = (half_t)(v - (float)hi);
  }
}

// ---------------- embed gather: Hh/Hl (N x 128 split f16) ------------------
__global__ __launch_bounds__(256) void embed_k(const int* __restrict__ nf,
                                               const float* __restrict__ emb,
                                               half_t* __restrict__ Hh,
                                               half_t* __restrict__ Hl) {
  int idx = blockIdx.x * 256 + threadIdx.x;  // over N*32 float4s
  int n = idx >> 5;
  int d4 = idx & 31;
  int a = nf[n];
  float4 v = *(const float4*)(emb + (size_t)a * 128 + d4 * 4);
  h4 hi, lo;
  const float* vp = &v.x;
#pragma unroll
  for (int j = 0; j < 4; ++j) {
    half_t h = (half_t)vp[j];
    hi[j] = h;
    lo[j] = (half_t)(vp[j] - (float)h);
  }
  *(h4*)(Hh + (size_t)n * 128 + d4 * 4) = hi;
  *(h4*)(Hl + (size_t)n * 128 + d4 * 4) = lo;
}

// ---------------- K1: 3-output GEMM over the 64-row tile -------------------
// y=0: preA[N][128] row-major (no bias)
// y=1: b -> Agg[N][384] cols 0..127 (bias = preb)
// y=2: postC = h-part of post-GEMM + postb, C-fragment-major f32
__global__ __launch_bounds__(256) void gemm3_k(const half_t* __restrict__ Ah_g,
                                               const half_t* __restrict__ Al_g,
                                               const half_t* __restrict__ WH,  // + l*49152
                                               const half_t* __restrict__ WL,
                                               const float* __restrict__ biasB,  // preb_l
                                               const float* __restrict__ biasP,  // postb_l
                                               float* __restrict__ preA,
                                               float* __restrict__ Agg,
                                               float* __restrict__ postC) {
  __shared__ half_t Ahs[64][132];
  __shared__ half_t Als[64][132];
  const int tid = threadIdx.x;
  const int bid = blockIdx.x;                      // 0..399
  const int y = blockIdx.y;                        // 0..2
  const int swz = (bid & 7) * 50 + (bid >> 3);     // XCD-contiguous rows
  const int r0 = swz * 64;
  const int wid = tid >> 6, lane = tid & 63;
  const int wm = wid >> 1, wn = wid & 1;
  const int lr = lane & 15, lk = (lane >> 4) * 8;
  f32x4 acc[2][4] = {};

  // stage full A tile (64 x 128, hi+lo)
  {
    const int row = tid >> 2;
#pragma unroll
    for (int s = 0; s < 4; ++s) {
      const int koff = (tid & 3) * 8 + s * 32;
      const size_t g = (size_t)(r0 + row) * 128 + koff;
      *(h8*)&Ahs[row][koff] = *(const h8*)(Ah_g + g);
      *(h8*)&Als[row][koff] = *(const h8*)(Al_g + g);
    }
  }
  __syncthreads();

  const half_t* WHs = WH + y * 16384;
  const half_t* WLs = WL + y * 16384;
#pragma unroll
  for (int kc = 0; kc < 4; ++kc) {
    h8 af[2][2];
#pragma unroll
    for (int mi = 0; mi < 2; ++mi) {
      const int r = wm * 32 + mi * 16 + lr;
      af[mi][0] = *(const h8*)&Ahs[r][kc * 32 + lk];
      af[mi][1] = *(const h8*)&Als[r][kc * 32 + lk];
    }
#pragma unroll
    for (int nj = 0; nj < 4; ++nj) {
      const size_t fi = ((size_t)((wn * 4 + nj) * 4 + kc) * 64 + lane) * 8;
      const h8 b0v = *(const h8*)(WHs + fi);
      const h8 b1v = *(const h8*)(WLs + fi);
#pragma unroll
      for (int mi = 0; mi < 2; ++mi) {
        acc[mi][nj] = __builtin_amdgcn_mfma_f32_16x16x32_f16(af[mi][0], b0v, acc[mi][nj], 0, 0, 0);
        acc[mi][nj] = __builtin_amdgcn_mfma_f32_16x16x32_f16(af[mi][0], b1v, acc[mi][nj], 0, 0, 0);
        acc[mi][nj] = __builtin_amdgcn_mfma_f32_16x16x32_f16(af[mi][1], b0v, acc[mi][nj], 0, 0, 0);
      }
    }
  }
  // epilogue: C/D layout col=lane&15, row=(lane>>4)*4+q
#pragma unroll
  for (int mi = 0; mi < 2; ++mi) {
    const int rowb = r0 + wm * 32 + mi * 16 + (lane >> 4) * 4;
#pragma unroll
    for (int nj = 0; nj < 4; ++nj) {
      const int col = wn * 64 + nj * 16 + lr;
      if (y == 0) {
#pragma unroll
        for (int q = 0; q < 4; ++q)
          preA[(size_t)(rowb + q) * 128 + col] = acc[mi][nj][q];
      } else if (y == 1) {
        const float bv = biasB[col];
#pragma unroll
        for (int q = 0; q < 4; ++q)
          Agg[(size_t)(rowb + q) * 384 + col] = acc[mi][nj][q] + bv;
      } else {
        const float bv = biasP[col];
        f32x4 v = acc[mi][nj];
        v[0] += bv; v[1] += bv; v[2] += bv; v[3] += bv;
        const int rowtile = swz * 4 + wm * 2 + mi;
        *(f32x4*)&postC[((size_t)(rowtile * 8 + wn * 4 + nj) * 64 + lane) * 4] = v;
      }
    }
  }
}

// ---------------- K2: edge aggregation (wave = node, max TLP) --------------
__global__ __launch_bounds__(256) void agg_k(const float* __restrict__ preA,
                                             const int* __restrict__ src,
                                             const float* __restrict__ eig,
                                             const half_t* __restrict__ Hh,
                                             const half_t* __restrict__ Hl,
                                             float* __restrict__ Agg) {
  const int bid = blockIdx.x;                       // 0..6399
  const int swz = (bid & 7) * 800 + (bid >> 3);     // XCD-contiguous
  const int wid = threadIdx.x >> 6, lane = threadIdx.x & 63;
  const int n = swz * 4 + wid;
  const int d0 = 2 * lane;
  int sv[KK];
  float wv[KK];
  {
    const int4* sp4 = (const int4*)(src + (size_t)n * KK);
    const float4* ep4 = (const float4*)(eig + (size_t)n * KK * 2);
#pragma unroll
    for (int t = 0; t < 4; ++t) {
      const int4 s4 = sp4[t];
      sv[4 * t + 0] = s4.x; sv[4 * t + 1] = s4.y;
      sv[4 * t + 2] = s4.z; sv[4 * t + 3] = s4.w;
    }
#pragma unroll
    for (int t = 0; t < 8; ++t) {
      const float4 e4 = ep4[t];
      wv[2 * t + 0] = e4.y; wv[2 * t + 1] = e4.w;
    }
  }
  const float2 b = *(const float2*)(Agg + (size_t)n * 384 + d0);
  const h2 hh2 = *(const h2*)(Hh + (size_t)n * 128 + d0);
  const h2 hl2 = *(const h2*)(Hl + (size_t)n * 128 + d0);
  const float hx = (float)hh2[0] + (float)hl2[0];
  const float hy = (float)hh2[1] + (float)hl2[1];
  float denom = 0.f;
#pragma unroll
  for (int e = 0; e < KK; ++e) denom += fabsf(wv[e]);
  denom += 1e-8f;
  const float inv = 1.f / denom;
  float sum_ew = 0.f;
#pragma unroll
  for (int e = 0; e < KK; ++e) {
    wv[e] *= inv;
    sum_ew += wv[e];
  }
  float sX = 0.f, sY = 0.f, wX = 0.f, wY = 0.f;
  float mX = -3.402823466e+38f, mY = -3.402823466e+38f;
#pragma unroll
  for (int e = 0; e < KK; ++e) {
    const float2 a = *(const float2*)(preA + (size_t)sv[e] * 128 + d0);
    sX += a.x; sY += a.y;
    wX = fmaf(wv[e], a.x, wX); wY = fmaf(wv[e], a.y, wY);
    mX = fmaxf(mX, a.x); mY = fmaxf(mY, a.y);
  }
  float* row = Agg + (size_t)n * 384;
  *(float2*)(row + d0) = {sX + 16.f * b.x, sY + 16.f * b.y};
  *(float2*)(row + 128 + d0) = {mX + b.x, mY + b.y};
  *(float2*)(row + 256 + d0) = {fabsf(wX + sum_ew * (b.x - hx)),
                                fabsf(wY + sum_ew * (b.y - hy))};
}

// ---------------- K3: agg-part GEMM (K=384) + epilogue ---------------------
// 32-row tiles, 800 blocks, 4 waves (wave tile 32x32). Agg staged to
// XOR-swizzled split-f16 LDS; C-init from postC (frag-major); W frag-major.
__global__ __launch_bounds__(256) void aggpost_k(const float* __restrict__ Agg,
                                                 const float* __restrict__ postC,
                                                 const half_t* __restrict__ WH,
                                                 const half_t* __restrict__ WL,
                                                 const float* __restrict__ snorm,
                                                 half_t* __restrict__ Hh,
                                                 half_t* __restrict__ Hl) {
  __shared__ half_t AhS[32 * 384];
  __shared__ half_t AlS[32 * 384];
  const int tid = threadIdx.x;
  const int bid = blockIdx.x;                       // 0..799
  const int swz = (bid & 7) * 100 + (bid >> 3);     // XCD-contiguous rows
  const int r0 = swz * 32;
  const int wid = tid >> 6, lane = tid & 63;
  const int wn = wid;                               // cols wn*32
  const int lr = lane & 15, ksub = lane >> 4;

  // stage: 32 rows x 384 f32 -> split-f16 LDS, XOR-swizzled.
  // Swizzle granule = 8 halves (matches the h8 read): write granule
  // g8 = (c>>1) ^ (r&7); a float4 (4 halves) lands at half-offset (c&1)*4.
#pragma unroll
  for (int it = 0; it < 12; ++it) {
    const int id = it * 256 + tid;
    const int r = id / 96, c = id % 96;             // c: float4 granule (4 f32)
    const float4 v = *(const float4*)(Agg + (size_t)(r0 + r) * 384 + c * 4);
    h4 hi, lo;
    const float* vp = &v.x;
#pragma unroll
    for (int j = 0; j < 4; ++j) {
      half_t h = (half_t)vp[j];
      hi[j] = h;
      lo[j] = (half_t)(vp[j] - (float)h);
    }
    const int g8 = (c >> 1) ^ (r & 7);              // 8-half granule, swizzled
    const int dst = r * 384 + (g8 << 3) + ((c & 1) << 2);
    *(h4*)&AhS[dst] = hi;
    *(h4*)&AlS[dst] = lo;
  }
  __syncthreads();

  // C-init from postC (fragment-major)
  f32x4 acc[2][2];
#pragma unroll
  for (int mi = 0; mi < 2; ++mi) {
    const int rowtile = swz * 2 + mi;
#pragma unroll
    for (int nj = 0; nj < 2; ++nj) {
      acc[mi][nj] = *(const f32x4*)&postC[((size_t)(rowtile * 8 + wn * 2 + nj) * 64 + lane) * 4];
    }
  }

  // main loop: K=384
#pragma unroll
  for (int kc = 0; kc < 12; ++kc) {
    h8 a0[2], a1[2];
#pragma unroll
    for (int mi = 0; mi < 2; ++mi) {
      const int row = mi * 16 + lr;
      const int cl = kc * 4 + ksub;                 // logical 8-half granule
      const int off = row * 384 + ((cl ^ (lr & 7)) << 3);
      a0[mi] = *(const h8*)&AhS[off];
      a1[mi] = *(const h8*)&AlS[off];
    }
#pragma unroll
    for (int nj = 0; nj < 2; ++nj) {
      const size_t fi = ((size_t)((wn * 2 + nj) * 12 + kc) * 64 + lane) * 8;
      const h8 b0v = *(const h8*)(WH + fi);
      const h8 b1v = *(const h8*)(WL + fi);
#pragma unroll
      for (int mi = 0; mi < 2; ++mi) {
        acc[mi][nj] = __builtin_amdgcn_mfma_f32_16x16x32_f16(a0[mi], b0v, acc[mi][nj], 0, 0, 0);
        acc[mi][nj] = __builtin_amdgcn_mfma_f32_16x16x32_f16(a0[mi], b1v, acc[mi][nj], 0, 0, 0);
        acc[mi][nj] = __builtin_amdgcn_mfma_f32_16x16x32_f16(a1[mi], b0v, acc[mi][nj], 0, 0, 0);
      }
    }
  }

  // epilogue: hn = h_old + relu(acc * snorm); write split-f16
#pragma unroll
  for (int mi = 0; mi < 2; ++mi) {
    const int rowb = r0 + mi * 16 + (lane >> 4) * 4;
#pragma unroll
    for (int nj = 0; nj < 2; ++nj) {
      const int col = wn * 32 + nj * 16 + lr;
#pragma unroll
      for (int q = 0; q < 4; ++q) {
        const int r = rowb + q;
        float a = acc[mi][nj][q];                   // includes postH0 + postb
        a *= snorm[r];
        a = fmaxf(a, 0.f);
        const size_t off = (size_t)r * 128 + col;
        const float hold = (float)Hh[off] + (float)Hl[off];
        const float hn = hold + a;
        const half_t hi = (half_t)hn;
        Hh[off] = hi;
        Hl[off] = (half_t)(hn - (float)hi);
      }
    }
  }
}

// ---------------- fused graph-mean + readout MLP (64 blocks) ---------------
__global__ __launch_bounds__(256) void reduce_mlp_k(const half_t* __restrict__ Hh,
                                                    const half_t* __restrict__ Hl,
                                                    const float* __restrict__ W0, const float* __restrict__ b0,
                                                    const float* __restrict__ W1, const float* __restrict__ b1,
                                                    const float* __restrict__ W2, const float* __restrict__ b2,
                                                    float* __restrict__ out) {
  __shared__ float hgs[128];
  __shared__ float red[128];
  __shared__ float y0s[64];
  __shared__ float y1s[32];
  __shared__ float wb[64 * 130];
  const int g = blockIdx.x;
  const int t = threadIdx.x;
  {
    const int d = t & 127, hf = t >> 7;
    const size_t base = ((size_t)g * NPG + (size_t)hf * 200) * 128 + d;
    float acc = 0.f;
    for (int i = 0; i < 200; ++i) {
      const size_t off = base + (size_t)i * 128;
      acc += (float)Hh[off] + (float)Hl[off];
    }
    if (hf) red[d] = acc;
    __syncthreads();
    if (!hf) hgs[d] = (acc + red[d]) * (1.f / (float)NPG);
  }
  __syncthreads();
  for (int idx = t; idx < 64 * 128; idx += 256) {
    wb[(idx >> 7) * 130 + (idx & 127)] = W0[idx];
  }
  __syncthreads();
  if (t < 64) {
    float a = b0[t];
    const float* w = &wb[t * 130];
    for (int k = 0; k < 128; ++k) a = fmaf(hgs[k], w[k], a);
    y0s[t] = fmaxf(a, 0.f);
  }
  __syncthreads();
  for (int idx = t; idx < 32 * 64; idx += 256) {
    wb[(idx >> 6) * 66 + (idx & 63)] = W1[idx];
  }
  __syncthreads();
  if (t < 32) {
    float a = b1[t];
    const float* w = &wb[t * 66];
    for (int k = 0; k < 64; ++k) a = fmaf(y0s[k], w[k], a);
    y1s[t] = fmaxf(a, 0.f);
  }
  __syncthreads();
  for (int idx = t; idx < 128 * 32; idx += 256) {
    wb[(idx >> 5) * 34 + (idx & 31)] = W2[idx];
  }
  __syncthreads();
  if (t < 128) {
    float a = b2[t];
    const float* w = &wb[t * 34];
    for (int k = 0; k < 32; ++k) a = fmaf(y1s[k], w[k], a);
    out[(size_t)g * 128 + t] = a;
  }
}

extern "C" void kernel_launch(void* const* d_in, const int* in_sizes, int n_in,
                              void* d_out, int out_size, void* d_ws, size_t ws_size,
                              hipStream_t stream) {
  const int* node_feat = (const int*)d_in[0];
  const int* src = (const int*)d_in[1];
  // d_in[2] = dst (repeat(arange(N),16)), unused
  const float* eig = (const float*)d_in[3];
  const float* snorm = (const float*)d_in[4];
  // d_in[5] = graph_ids, unused
  const float* emb = (const float*)d_in[6];
  const float* preW = (const float*)d_in[7];
  const float* preb = (const float*)d_in[8];
  const float* postW = (const float*)d_in[9];
  const float* postb = (const float*)d_in[10];
  const float* rW0 = (const float*)d_in[11];
  const float* rb0 = (const float*)d_in[12];
  const float* rW1 = (const float*)d_in[13];
  const float* rb1 = (const float*)d_in[14];
  const float* rW2 = (const float*)d_in[15];
  const float* rb2 = (const float*)d_in[16];
  float* out = (float*)d_out;

  half_t* Hh = (half_t*)d_ws;                          // N*128 halves
  half_t* Hl = Hh + (size_t)NN * 128;                  // N*128
  float* preA = (float*)(Hl + (size_t)NN * 128);       // N*128 f32
  float* Agg = preA + (size_t)NN * 128;                // N*384 f32
  float* postC = Agg + (size_t)NN * 384;               // N*128 f32 (frag-major)
  half_t* Wk1H = (half_t*)(postC + (size_t)NN * 128);  // L*49152
  half_t* Wk1L = Wk1H + (size_t)LL * 49152;
  half_t* WaggH = Wk1L + (size_t)LL * 49152;           // L*49152
  half_t* WaggL = WaggH + (size_t)LL * 49152;

  prep_k<<<1536, 256, 0, stream>>>(preW, postW, Wk1H, Wk1L, WaggH, WaggL);
  embed_k<<<(NN * 32) / 256, 256, 0, stream>>>(node_feat, emb, Hh, Hl);

  for (int l = 0; l < LL; ++l) {
    gemm3_k<<<dim3(400, 3), 256, 0, stream>>>(
        Hh, Hl, Wk1H + (size_t)l * 49152, Wk1L + (size_t)l * 49152,
        preb + (size_t)l * 128, postb + (size_t)l * 128,
        preA, Agg, postC);
    agg_k<<<NN / 4, 256, 0, stream>>>(preA, src, eig, Hh, Hl, Agg);
    aggpost_k<<<NN / 32, 256, 0, stream>>>(
        Agg, postC, WaggH + (size_t)l * 49152, WaggL + (size_t)l * 49152,
        snorm, Hh, Hl);
  }

  reduce_mlp_k<<<BB, 256, 0, stream>>>(Hh, Hl, rW0, rb0, rW1, rb1, rW2, rb2, out);
}

// Round 13
// 252.492 us; speedup vs baseline: 1.2492x; 1.2492x over previous
//
#include <hip/hip_runtime.h>
#include <cstddef>

#define NN 25600
#define BB 64
#define NPG 400
#define KK 16
#define LL 4

typedef _Float16 half_t;
typedef _Float16 h8 __attribute__((ext_vector_type(8)));
typedef _Float16 h4 __attribute__((ext_vector_type(4)));
typedef _Float16 h2 __attribute__((ext_vector_type(2)));
typedef float f32x4 __attribute__((ext_vector_type(4)));

#define GCAST(p) ((const __attribute__((address_space(1))) void*)(p))
#define SCAST(p) ((__attribute__((address_space(3))) void*)(p))

// ---------------- weight prep: split-fp16 weights in MFMA FRAGMENT order ----
__global__ __launch_bounds__(256) void prep_k(const float* __restrict__ preW,
                                              const float* __restrict__ preb,
                                              const float* __restrict__ postW,
                                              half_t* __restrict__ WpreH,
                                              half_t* __restrict__ WpreL,
                                              float* __restrict__ bpre,
                                              half_t* __restrict__ WpostH,
                                              half_t* __restrict__ WpostL) {
  int idx = blockIdx.x * 256 + threadIdx.x;
  const int n1 = LL * 256 * 128;          // 131072
  const int n2 = n1 + LL * 256;           // +1024
  const int n3 = n2 + LL * 128 * 512;     // +262144
  if (idx < n1) {
    int l = idx / 32768;
    int q = idx % 32768;
    int j = q & 7, lane = (q >> 3) & 63, kc = (q >> 9) & 3, c16 = q >> 11;  // c16 0..15
    int col = c16 * 16 + (lane & 15);
    int k = kc * 32 + (lane >> 4) * 8 + j;
    float v = (col < 128) ? preW[(size_t)l * 32768 + (size_t)col * 256 + k]
                          : preW[(size_t)l * 32768 + (size_t)(col - 128) * 256 + 128 + k];
    half_t hi = (half_t)v;
    WpreH[idx] = hi;
    WpreL[idx] = (half_t)(v - (float)hi);
  } else if (idx < n2) {
    int r = idx - n1;
    int l = r / 256, o = r % 256;
    bpre[r] = (o < 128) ? 0.f : preb[l * 128 + (o - 128)];
  } else if (idx < n3) {
    int r = idx - n2;
    int l = r / 65536;
    int q = r % 65536;
    int j = q & 7, lane = (q >> 3) & 63, kc = (q >> 9) & 15, c16 = q >> 13;  // c16 0..7
    int col = c16 * 16 + (lane & 15);
    int k = kc * 32 + (lane >> 4) * 8 + j;
    int jblk = k >> 7, kk = k & 127;
    const float* base = postW + (size_t)l * 128 * 640 + (size_t)col * 640;
    float v;
    if (jblk == 0)      v = base[kk];
    else if (jblk == 1) v = base[128 + kk] * (1.f / 16.f) + base[256 + kk];
    else if (jblk == 2) v = base[384 + kk];
    else                v = base[512 + kk];
    half_t hi = (half_t)v;
    WpostH[r] = hi;
    WpostL[r] = (half_t)(v - (float)hi);
  }
}

// ---------------- embed gather: Hh/Hl (N x 128 split f16) ------------------
__global__ __launch_bounds__(256) void embed_k(const int* __restrict__ nf,
                                               const float* __restrict__ emb,
                                               half_t* __restrict__ Hh,
                                               half_t* __restrict__ Hl) {
  int idx = blockIdx.x * 256 + threadIdx.x;  // over N*32 float4s
  int n = idx >> 5;
  int d4 = idx & 31;
  int a = nf[n];
  float4 v = *(const float4*)(emb + (size_t)a * 128 + d4 * 4);
  h4 hi, lo;
  const float* vp = &v.x;
#pragma unroll
  for (int j = 0; j < 4; ++j) {
    half_t h = (half_t)vp[j];
    hi[j] = h;
    lo[j] = (half_t)(vp[j] - (float)h);
  }
  *(h4*)(Hh + (size_t)n * 128 + d4 * 4) = hi;
  *(h4*)(Hl + (size_t)n * 128 + d4 * 4) = lo;
}

// ---------------- pre-GEMM (A-side only): preA[N x 128] = Hcat @ WpA^T -----
__global__ __launch_bounds__(256) void pre_gemm_k(const half_t* __restrict__ Ah_g,
                                                  const half_t* __restrict__ Al_g,
                                                  const half_t* __restrict__ Wh_g,
                                                  const half_t* __restrict__ Wl_g,
                                                  float* __restrict__ preA) {
  __shared__ half_t Ahs[64][132];
  __shared__ half_t Als[64][132];
  const int tid = threadIdx.x;
  const int bid = blockIdx.x;                      // 0..399
  const int swz = (bid & 7) * 50 + (bid >> 3);     // XCD-contiguous rows
  const int r0 = swz * 64;
  const int wid = tid >> 6, lane = tid & 63;
  const int wm = wid >> 1, wn = wid & 1;
  const int lr = lane & 15, lk = (lane >> 4) * 8;
  f32x4 acc[2][4] = {};

  // stage full A tile (64 x 128, hi+lo)
  {
    const int row = tid >> 2;
#pragma unroll
    for (int s = 0; s < 4; ++s) {
      const int koff = (tid & 3) * 8 + s * 32;
      const size_t g = (size_t)(r0 + row) * 128 + koff;
      *(h8*)&Ahs[row][koff] = *(const h8*)(Ah_g + g);
      *(h8*)&Als[row][koff] = *(const h8*)(Al_g + g);
    }
  }
  __syncthreads();

#pragma unroll
  for (int kc = 0; kc < 4; ++kc) {
    h8 af[2][2];
#pragma unroll
    for (int mi = 0; mi < 2; ++mi) {
      const int r = wm * 32 + mi * 16 + lr;
      af[mi][0] = *(const h8*)&Ahs[r][kc * 32 + lk];
      af[mi][1] = *(const h8*)&Als[r][kc * 32 + lk];
    }
#pragma unroll
    for (int nj = 0; nj < 4; ++nj) {
      const size_t fi = ((size_t)((wn * 4 + nj) * 4 + kc) * 64 + lane) * 8;
      const h8 b0v = *(const h8*)(Wh_g + fi);
      const h8 b1v = *(const h8*)(Wl_g + fi);
#pragma unroll
      for (int mi = 0; mi < 2; ++mi) {
        acc[mi][nj] = __builtin_amdgcn_mfma_f32_16x16x32_f16(af[mi][0], b0v, acc[mi][nj], 0, 0, 0);
        acc[mi][nj] = __builtin_amdgcn_mfma_f32_16x16x32_f16(af[mi][0], b1v, acc[mi][nj], 0, 0, 0);
        acc[mi][nj] = __builtin_amdgcn_mfma_f32_16x16x32_f16(af[mi][1], b0v, acc[mi][nj], 0, 0, 0);
      }
    }
  }
  // epilogue: C/D layout col=lane&15, row=(lane>>4)*4+q
#pragma unroll
  for (int mi = 0; mi < 2; ++mi) {
    const int rowb = r0 + wm * 32 + mi * 16 + (lane >> 4) * 4;
#pragma unroll
    for (int nj = 0; nj < 4; ++nj) {
      const int col = wn * 64 + nj * 16 + lr;
#pragma unroll
      for (int q = 0; q < 4; ++q) {
        preA[(size_t)(rowb + q) * 128 + col] = acc[mi][nj][q];
      }
    }
  }
}

// ---------------- fused B-side pre-GEMM + edge-agg + post-GEMM -------------
// block = 16 nodes, 4 waves. Gathers staged via async global_load_lds; every
// DMA re-issue to a reused LDS buffer is guarded by lgkmcnt(0) (DS queue
// drain) to order prior ds_reads against the DMA write. Step C prefetches
// W fragments one kc ahead into named registers.
__global__ __launch_bounds__(256, 2) void agg_post_k(const float* __restrict__ preA,  // N x 128
                                                     const int* __restrict__ src,
                                                     const float* __restrict__ eig,   // E x 2
                                                     const half_t* __restrict__ WpHg, // pre frag-major
                                                     const half_t* __restrict__ WpLg,
                                                     const float* __restrict__ bpre128, // B-side bias
                                                     half_t* __restrict__ Hh,         // N x 128 (in/out)
                                                     half_t* __restrict__ Hl,
                                                     const half_t* __restrict__ Wh,   // post frag-major
                                                     const half_t* __restrict__ Wl,
                                                     const float* __restrict__ bias,  // 128
                                                     const float* __restrict__ snorm) {
  __shared__ half_t Ah[16][392];
  __shared__ half_t Al[16][392];
  __shared__ float bsh[16][132];
  __shared__ float stage[4][8][128];               // per-wave gather staging
  const int tid = threadIdx.x;
  const int bid = blockIdx.x;                       // 0..1599
  const int swz = (bid & 7) * 200 + (bid >> 3);     // XCD-contiguous nodes
  const int r0 = swz * 16;
  const int wid = tid >> 6, lane = tid & 63;
  const int wn = wid;                               // 4 waves split 128 cols
  const int lr = lane & 15, lk = (lane >> 4) * 8;
  const int d0 = 2 * lane;
  const int glane = (lane & 31) * 4;                // float offset within row
  const int gsel = lane >> 5;                       // 0/1: which row of the pair

  // prefetch h fragments for this block's 16 rows
  const int frow = r0 + lr;
  h8 afh[4][2];
#pragma unroll
  for (int hc = 0; hc < 4; ++hc) {
    afh[hc][0] = *(const h8*)(Hh + (size_t)frow * 128 + hc * 32 + lk);
    afh[hc][1] = *(const h8*)(Hl + (size_t)frow * 128 + hc * 32 + lk);
  }

  // ---- step A: b = Hcat @ WpB^T + bias(B-side) -> bsh[16][128] ----
  {
    f32x4 bacc[2] = {};
#pragma unroll
    for (int kc = 0; kc < 4; ++kc) {
#pragma unroll
      for (int nj = 0; nj < 2; ++nj) {
        const size_t fi = ((size_t)((8 + wn * 2 + nj) * 4 + kc) * 64 + lane) * 8;
        const h8 b0v = *(const h8*)(WpHg + fi);
        const h8 b1v = *(const h8*)(WpLg + fi);
        bacc[nj] = __builtin_amdgcn_mfma_f32_16x16x32_f16(afh[kc][0], b0v, bacc[nj], 0, 0, 0);
        bacc[nj] = __builtin_amdgcn_mfma_f32_16x16x32_f16(afh[kc][0], b1v, bacc[nj], 0, 0, 0);
        bacc[nj] = __builtin_amdgcn_mfma_f32_16x16x32_f16(afh[kc][1], b0v, bacc[nj], 0, 0, 0);
      }
    }
    const int rowb = (lane >> 4) * 4;
#pragma unroll
    for (int nj = 0; nj < 2; ++nj) {
      const int col = (wn * 2 + nj) * 16 + lr;
      const float bv = bpre128[col];
#pragma unroll
      for (int q = 0; q < 4; ++q) {
        bsh[rowb + q][col] = bacc[nj][q] + bv;
      }
    }
  }
  __syncthreads();

  // ---- step B: aggregation, 4 nodes per wave, async-staged gathers ----
  for (int i = 0; i < 4; ++i) {
    const int lrow = wid * 4 + i;
    const int n = r0 + lrow;
    int sv[KK];
    float wv[KK];
    {
      const int4* sp4 = (const int4*)(src + (size_t)n * KK);
      const float4* ep4 = (const float4*)(eig + (size_t)n * KK * 2);
#pragma unroll
      for (int t = 0; t < 4; ++t) {
        const int4 s4 = sp4[t];
        sv[4 * t + 0] = s4.x;
        sv[4 * t + 1] = s4.y;
        sv[4 * t + 2] = s4.z;
        sv[4 * t + 3] = s4.w;
      }
#pragma unroll
      for (int t = 0; t < 8; ++t) {
        const float4 e4 = ep4[t];
        wv[2 * t + 0] = e4.y;
        wv[2 * t + 1] = e4.w;
      }
    }
    // drain DS queue before re-targeting the stage buffer (race guard),
    // then issue chunk 0 (rows 0..7) as 4 DMA instructions
    asm volatile("s_waitcnt lgkmcnt(0)" ::: "memory");
#pragma unroll
    for (int c = 0; c < 4; ++c) {
      const int e = 2 * c + gsel;
      const float* gp = preA + (size_t)sv[e] * 128 + glane;
      __builtin_amdgcn_global_load_lds(GCAST(gp), SCAST(&stage[wid][2 * c][0]), 16, 0, 0);
    }
    // weights (VALU overlaps DMA)
    float denom = 0.f;
#pragma unroll
    for (int e = 0; e < KK; ++e) denom += fabsf(wv[e]);
    denom += 1e-8f;
    const float inv = 1.f / denom;
    float sum_ew = 0.f;
#pragma unroll
    for (int e = 0; e < KK; ++e) {
      wv[e] *= inv;
      sum_ew += wv[e];
    }
    float sA0 = 0.f, sA1 = 0.f, wA0 = 0.f, wA1 = 0.f;
    float mA0 = -3.402823466e+38f, mA1 = -3.402823466e+38f;
    asm volatile("s_waitcnt vmcnt(0)" ::: "memory");
#pragma unroll
    for (int e = 0; e < 8; ++e) {
      const float2 a = *(const float2*)&stage[wid][e][d0];
      sA0 += a.x;
      sA1 += a.y;
      wA0 = fmaf(wv[e], a.x, wA0);
      wA1 = fmaf(wv[e], a.y, wA1);
      mA0 = fmaxf(mA0, a.x);
      mA1 = fmaxf(mA1, a.y);
    }
    // drain DS queue (chunk-0 reads retired), then issue chunk 1 (rows 8..15)
    asm volatile("s_waitcnt lgkmcnt(0)" ::: "memory");
#pragma unroll
    for (int c = 0; c < 4; ++c) {
      const int e = 8 + 2 * c + gsel;
      const float* gp = preA + (size_t)sv[e] * 128 + glane;
      __builtin_amdgcn_global_load_lds(GCAST(gp), SCAST(&stage[wid][2 * c][0]), 16, 0, 0);
    }
    asm volatile("s_waitcnt vmcnt(0)" ::: "memory");
#pragma unroll
    for (int e = 0; e < 8; ++e) {
      const float2 a = *(const float2*)&stage[wid][e][d0];
      const float w = wv[8 + e];
      sA0 += a.x;
      sA1 += a.y;
      wA0 = fmaf(w, a.x, wA0);
      wA1 = fmaf(w, a.y, wA1);
      mA0 = fmaxf(mA0, a.x);
      mA1 = fmaxf(mA1, a.y);
    }
    const float2 b = {bsh[lrow][d0], bsh[lrow][d0 + 1]};
    const h2 hh2 = *(const h2*)(Hh + (size_t)n * 128 + d0);
    const h2 hl2 = *(const h2*)(Hl + (size_t)n * 128 + d0);
    const float hx = (float)hh2[0] + (float)hl2[0];
    const float hy = (float)hh2[1] + (float)hl2[1];
    auto wr2 = [&](int kcol, float v0, float v1) {
      h2 hi, lo;
      hi[0] = (half_t)v0;
      hi[1] = (half_t)v1;
      lo[0] = (half_t)(v0 - (float)hi[0]);
      lo[1] = (half_t)(v1 - (float)hi[1]);
      *(h2*)&Ah[lrow][kcol] = hi;
      *(h2*)&Al[lrow][kcol] = lo;
    };
    wr2(d0, sA0 + 16.f * b.x, sA1 + 16.f * b.y);
    wr2(128 + d0, mA0 + b.x, mA1 + b.y);
    wr2(256 + d0, fabsf(wA0 + sum_ew * (b.x - hx)), fabsf(wA1 + sum_ew * (b.y - hy)));
  }
  __syncthreads();

  // ---- step C: GEMM over K=512, wave tile 16 x 32, W prefetched 1 kc ahead
  f32x4 acc[2] = {};
  h8 wc0[2], wc1[2];
#pragma unroll
  for (int nj = 0; nj < 2; ++nj) {
    const size_t fi = ((size_t)((wn * 2 + nj) * 16 + 0) * 64 + lane) * 8;
    wc0[nj] = *(const h8*)(Wh + fi);
    wc1[nj] = *(const h8*)(Wl + fi);
  }
#pragma unroll
  for (int kc = 0; kc < 16; ++kc) {
    h8 a0, a1;
    if (kc < 4) {
      a0 = afh[kc & 3][0];
      a1 = afh[kc & 3][1];
    } else {
      a0 = *(const h8*)&Ah[lr][(kc - 4) * 32 + lk];
      a1 = *(const h8*)&Al[lr][(kc - 4) * 32 + lk];
    }
    h8 wn0[2], wn1[2];
    if (kc < 15) {
#pragma unroll
      for (int nj = 0; nj < 2; ++nj) {
        const size_t fi = ((size_t)((wn * 2 + nj) * 16 + (kc + 1)) * 64 + lane) * 8;
        wn0[nj] = *(const h8*)(Wh + fi);
        wn1[nj] = *(const h8*)(Wl + fi);
      }
    }
#pragma unroll
    for (int nj = 0; nj < 2; ++nj) {
      acc[nj] = __builtin_amdgcn_mfma_f32_16x16x32_f16(a0, wc0[nj], acc[nj], 0, 0, 0);
      acc[nj] = __builtin_amdgcn_mfma_f32_16x16x32_f16(a0, wc1[nj], acc[nj], 0, 0, 0);
      acc[nj] = __builtin_amdgcn_mfma_f32_16x16x32_f16(a1, wc0[nj], acc[nj], 0, 0, 0);
    }
    if (kc < 15) {
      wc0[0] = wn0[0]; wc0[1] = wn0[1];
      wc1[0] = wn1[0]; wc1[1] = wn1[1];
    }
  }

  // ---- epilogue: hn = h_old + relu((acc+bias)*snorm); write split-f16 -----
  const int rowb = r0 + (lane >> 4) * 4;
#pragma unroll
  for (int nj = 0; nj < 2; ++nj) {
    const int col = wn * 32 + nj * 16 + lr;
    const float bv = bias[col];
#pragma unroll
    for (int q = 0; q < 4; ++q) {
      const int r = rowb + q;
      float a = acc[nj][q] + bv;
      a *= snorm[r];
      a = fmaxf(a, 0.f);
      const size_t off = (size_t)r * 128 + col;
      const float hold = (float)Hh[off] + (float)Hl[off];
      const float hn = hold + a;
      const half_t hi = (half_t)hn;
      Hh[off] = hi;
      Hl[off] = (half_t)(hn - (float)hi);
    }
  }
}

// ---------------- fused graph-mean + readout MLP (64 blocks) ---------------
__global__ __launch_bounds__(256) void reduce_mlp_k(const half_t* __restrict__ Hh,
                                                    const half_t* __restrict__ Hl,
                                                    const float* __restrict__ W0, const float* __restrict__ b0,
                                                    const float* __restrict__ W1, const float* __restrict__ b1,
                                                    const float* __restrict__ W2, const float* __restrict__ b2,
                                                    float* __restrict__ out) {
  __shared__ float hgs[128];
  __shared__ float red[128];
  __shared__ float y0s[64];
  __shared__ float y1s[32];
  __shared__ float wb[64 * 130];
  const int g = blockIdx.x;
  const int t = threadIdx.x;
  {
    const int d = t & 127, hf = t >> 7;
    const size_t base = ((size_t)g * NPG + (size_t)hf * 200) * 128 + d;
    float acc = 0.f;
    for (int i = 0; i < 200; ++i) {
      const size_t off = base + (size_t)i * 128;
      acc += (float)Hh[off] + (float)Hl[off];
    }
    if (hf) red[d] = acc;
    __syncthreads();
    if (!hf) hgs[d] = (acc + red[d]) * (1.f / (float)NPG);
  }
  __syncthreads();
  for (int idx = t; idx < 64 * 128; idx += 256) {
    wb[(idx >> 7) * 130 + (idx & 127)] = W0[idx];
  }
  __syncthreads();
  if (t < 64) {
    float a = b0[t];
    const float* w = &wb[t * 130];
    for (int k = 0; k < 128; ++k) a = fmaf(hgs[k], w[k], a);
    y0s[t] = fmaxf(a, 0.f);
  }
  __syncthreads();
  for (int idx = t; idx < 32 * 64; idx += 256) {
    wb[(idx >> 6) * 66 + (idx & 63)] = W1[idx];
  }
  __syncthreads();
  if (t < 32) {
    float a = b1[t];
    const float* w = &wb[t * 66];
    for (int k = 0; k < 64; ++k) a = fmaf(y0s[k], w[k], a);
    y1s[t] = fmaxf(a, 0.f);
  }
  __syncthreads();
  for (int idx = t; idx < 128 * 32; idx += 256) {
    wb[(idx >> 5) * 34 + (idx & 31)] = W2[idx];
  }
  __syncthreads();
  if (t < 128) {
    float a = b2[t];
    const float* w = &wb[t * 34];
    for (int k = 0; k < 32; ++k) a = fmaf(y1s[k], w[k], a);
    out[(size_t)g * 128 + t] = a;
  }
}

extern "C" void kernel_launch(void* const* d_in, const int* in_sizes, int n_in,
                              void* d_out, int out_size, void* d_ws, size_t ws_size,
                              hipStream_t stream) {
  const int* node_feat = (const int*)d_in[0];
  const int* src = (const int*)d_in[1];
  // d_in[2] = dst (repeat(arange(N),16)), unused
  const float* eig = (const float*)d_in[3];
  const float* snorm = (const float*)d_in[4];
  // d_in[5] = graph_ids, unused
  const float* emb = (const float*)d_in[6];
  const float* preW = (const float*)d_in[7];
  const float* preb = (const float*)d_in[8];
  const float* postW = (const float*)d_in[9];
  const float* postb = (const float*)d_in[10];
  const float* rW0 = (const float*)d_in[11];
  const float* rb0 = (const float*)d_in[12];
  const float* rW1 = (const float*)d_in[13];
  const float* rb1 = (const float*)d_in[14];
  const float* rW2 = (const float*)d_in[15];
  const float* rb2 = (const float*)d_in[16];
  float* out = (float*)d_out;

  half_t* Hh = (half_t*)d_ws;                        // N*128
  half_t* Hl = Hh + (size_t)NN * 128;                // N*128
  float* preA = (float*)(Hl + (size_t)NN * 128);     // N*128 f32 (gathered)
  half_t* WpreH = (half_t*)(preA + (size_t)NN * 128); // L*256*128 frag-major
  half_t* WpreL = WpreH + (size_t)LL * 32768;
  half_t* WpostH = WpreL + (size_t)LL * 32768;       // L*128*512 frag-major
  half_t* WpostL = WpostH + (size_t)LL * 65536;
  float* bpre = (float*)(WpostL + (size_t)LL * 65536); // L*256

  prep_k<<<1540, 256, 0, stream>>>(preW, preb, postW, WpreH, WpreL, bpre, WpostH, WpostL);
  embed_k<<<(NN * 32) / 256, 256, 0, stream>>>(node_feat, emb, Hh, Hl);

  for (int l = 0; l < LL; ++l) {
    pre_gemm_k<<<NN / 64, 256, 0, stream>>>(
        Hh, Hl, WpreH + (size_t)l * 32768, WpreL + (size_t)l * 32768, preA);
    agg_post_k<<<NN / 16, 256, 0, stream>>>(
        preA, src, eig,
        WpreH + (size_t)l * 32768, WpreL + (size_t)l * 32768,
        bpre + (size_t)l * 256 + 128,
        Hh, Hl,
        WpostH + (size_t)l * 65536, WpostL + (size_t)l * 65536,
        postb + (size_t)l * 128, snorm);
  }

  reduce_mlp_k<<<BB, 256, 0, stream>>>(Hh, Hl, rW0, rb0, rW1, rb1, rW2, rb2, out);
}